// Round 3
// baseline (422.774 us; speedup 1.0000x reference)
//
#include <hip/hip_runtime.h>
#include <math.h>

// Problem constants: B=4, M=8192, D=512, N=128, P=1
#define B_ 4
#define M_ 8192
#define D_ 512
#define N_ 128
#define TOK (B_ * M_)    // 32768
#define NSL 8            // xs accumulator slices (one per XCD)

// Workspace layout (float offsets). colsum and xsa are adjacent -> one memset.
#define OFF_CS 0                                    // [512] colsum of raw exp
#define OFF_XSA 512                                 // [NSL][B][N][D] fp32 partial xs
#define OFF_PBT (OFF_XSA + NSL * B_ * N_ * D_)      // [N*D] bf16 phi^T (shorts)
#define OFF_E (OFF_PBT + N_ * D_ / 2)               // [TOK*N] raw exp(logits) fp32
#define OFF_YST (OFF_E + (size_t)TOK * N_)          // [B*D*N] bf16 ys^T (shorts)

typedef __attribute__((ext_vector_type(8))) short s16x8;
typedef __attribute__((ext_vector_type(4))) float f32x4;

__device__ inline short f2bf(float f) {  // RNE round to bf16
    union { float f; unsigned u; } v;
    v.f = f;
    unsigned r = v.u + 0x7fffu + ((v.u >> 16) & 1u);
    return (short)(r >> 16);
}

// ---------------------------------------------------------------------------
// K0: phi col-normalize -> pbt[n][d] bf16 = scale * phi[d][n]/max(||phi[:,n]||,eps)
__global__ __launch_bounds__(128) void k_phinorm(const float* __restrict__ phi,
                                                 const float* __restrict__ scale,
                                                 short* __restrict__ pbt) {
    __shared__ float sred[128];
    int n = blockIdx.x, tid = threadIdx.x;
    float ss = 0.f;
    for (int d = tid; d < D_; d += 128) {
        float v = phi[d * N_ + n];
        ss += v * v;
    }
    sred[tid] = ss;
    __syncthreads();
    for (int s = 64; s > 0; s >>= 1) {
        if (tid < s) sred[tid] += sred[tid + s];
        __syncthreads();
    }
    float sc = scale[0] / fmaxf(sqrtf(sred[0]), 1e-12f);
    for (int d = tid; d < D_; d += 128) pbt[n * D_ + d] = f2bf(phi[d * N_ + n] * sc);
}

// ---------------------------------------------------------------------------
// K1: mega-kernel. Tile 64m x 128n, 256 thr (4 waves, each 16m x 128n).
// Phase 1: logits GEMM on raw bf16(x) (rn applied in epilogue). During the
//   K-loop each wave register-captures its 128-d strip of x^T (bf2[8][2]).
// Epilogue: E = exp(rn*dot) fp32, colsum atomics, ebf = bf16(E*rn).
// Phase 2: xs-partial GEMM  sum_m ebf[n][m]*xT[d][m]  via MFMA with A = P-tile
//   transposed in LDS (two 64-n halves), B = bf2 registers; unsafeAtomicAdd
//   into per-slice xsa[slice][b][n][d]  (slice = blockIdx&7 -> L2-local).
__global__ __launch_bounds__(256) void k_logits(const float* __restrict__ x,
                                                const short* __restrict__ pbt,
                                                float* __restrict__ E,
                                                float* __restrict__ colsum,
                                                float* __restrict__ xsa) {
    __shared__ short smem[64 * 40 + 128 * 40];  // As[64][40] | Bs[128][40]; T overlays
    __shared__ float rnS[64];
    short* As = smem;
    short* Bs = smem + 64 * 40;
    short* T = smem;  // [64][72] phase-2 P^T tile (9216 B <= 15360 B)

    int t = threadIdx.x;
    int r0 = blockIdx.x * 64;
    int slice = blockIdx.x & 7;
    int sma = t >> 2, kqa = (t & 3) * 8;   // A staging: 64 rows x 4 k-groups
    int smb = t >> 1, khb = (t & 1) * 16;  // B staging: 128 rows x 2 k-halves
    const float* xrow = &x[(size_t)(r0 + sma) * D_ + kqa];
    const short* brow = &pbt[smb * D_ + khb];
    int wid = t >> 6, lane = t & 63;
    int quad = lane >> 4, l15 = lane & 15;
    int mw = wid * 16;
    f32x4 acc[8] = {};
    s16x8 bf2[8][2];  // captured x^T strip: d = wid*128 + dj*16 + l15, m = mk*32+quad*8+e
    float ss = 0.f;

#pragma unroll
    for (int kt = 0; kt < 16; kt++) {
        int k0 = kt * 32;
        float4 a0 = *(const float4*)&xrow[k0];
        float4 a1 = *(const float4*)&xrow[k0 + 4];
        ss += a0.x * a0.x + a0.y * a0.y + a0.z * a0.z + a0.w * a0.w +
              a1.x * a1.x + a1.y * a1.y + a1.z * a1.z + a1.w * a1.w;
        s16x8 av;
        av[0] = f2bf(a0.x); av[1] = f2bf(a0.y); av[2] = f2bf(a0.z); av[3] = f2bf(a0.w);
        av[4] = f2bf(a1.x); av[5] = f2bf(a1.y); av[6] = f2bf(a1.z); av[7] = f2bf(a1.w);
        s16x8 bv0 = *(const s16x8*)&brow[k0];
        s16x8 bv1 = *(const s16x8*)&brow[k0 + 8];
        *(s16x8*)&As[sma * 40 + kqa] = av;
        *(s16x8*)&Bs[smb * 40 + khb] = bv0;
        *(s16x8*)&Bs[smb * 40 + khb + 8] = bv1;
        __syncthreads();
        s16x8 af = *(const s16x8*)&As[(mw + l15) * 40 + quad * 8];
        s16x8 bfr[8];
#pragma unroll
        for (int j = 0; j < 8; j++)
            bfr[j] = *(const s16x8*)&Bs[(j * 16 + l15) * 40 + quad * 8];
#pragma unroll
        for (int j = 0; j < 8; j++)
            acc[j] = __builtin_amdgcn_mfma_f32_16x16x32_bf16(af, bfr[j], acc[j], 0, 0, 0);
        if ((kt >> 2) == wid) {  // this iter carries this wave's d-strip slice
#pragma unroll
            for (int djl = 0; djl < 2; djl++)
#pragma unroll
                for (int mk = 0; mk < 2; mk++) {
                    s16x8 tv;
#pragma unroll
                    for (int jj = 0; jj < 8; jj++)
                        tv[jj] = As[(mk * 32 + quad * 8 + jj) * 40 + djl * 16 + l15];
                    bf2[(kt & 3) * 2 + djl][mk] = tv;
                }
        }
        __syncthreads();
    }
    // row inverse norms: 4 consecutive lanes share a row
    ss += __shfl_xor(ss, 1, 64);
    ss += __shfl_xor(ss, 2, 64);
    if ((t & 3) == 0) rnS[sma] = 1.0f / fmaxf(sqrtf(ss), 1e-12f);
    __syncthreads();

    int bb = r0 >> 13;
    float rv0 = rnS[mw + quad * 4 + 0], rv1 = rnS[mw + quad * 4 + 1];
    float rv2 = rnS[mw + quad * 4 + 2], rv3 = rnS[mw + quad * 4 + 3];
    short4 ebf[8];
#pragma unroll
    for (int j = 0; j < 8; j++) {
        int n = j * 16 + l15;
        int mb = r0 + mw + quad * 4;
        f32x4 vv = acc[j];
        float e0 = __expf(vv[0] * rv0), e1 = __expf(vv[1] * rv1);
        float e2 = __expf(vv[2] * rv2), e3 = __expf(vv[3] * rv3);
        float cs = e0 + e1 + e2 + e3;
        E[(size_t)(mb + 0) * N_ + n] = e0;
        E[(size_t)(mb + 1) * N_ + n] = e1;
        E[(size_t)(mb + 2) * N_ + n] = e2;
        E[(size_t)(mb + 3) * N_ + n] = e3;
        short4 eb = {f2bf(e0 * rv0), f2bf(e1 * rv1), f2bf(e2 * rv2), f2bf(e3 * rv3)};
        ebf[j] = eb;
        cs += __shfl_xor(cs, 16, 64);
        cs += __shfl_xor(cs, 32, 64);
        if (lane < 16) unsafeAtomicAdd(&colsum[bb * N_ + n], cs);
    }

    // Phase 2: xs partial, two 64-n halves. A = T (P^T), B = bf2 regs.
    size_t xbase = (size_t)slice * (B_ * N_ * D_) + (size_t)bb * (N_ * D_);
    int dstrip = wid * 128;
#pragma unroll
    for (int h = 0; h < 2; h++) {
        __syncthreads();  // protect T region (As/Bs reads done / prev-half reads done)
#pragma unroll
        for (int j = 0; j < 4; j++) {
            int nl = j * 16 + l15;
            *(short4*)&T[nl * 72 + mw + quad * 4] = ebf[h * 4 + j];
        }
        __syncthreads();
#pragma unroll
        for (int p = 0; p < 2; p++) {
            f32x4 c2[4][4] = {};
#pragma unroll
            for (int mk = 0; mk < 2; mk++) {
                s16x8 af2[4];
#pragma unroll
                for (int nb = 0; nb < 4; nb++)
                    af2[nb] = *(const s16x8*)&T[(nb * 16 + l15) * 72 + mk * 32 + quad * 8];
#pragma unroll
                for (int nb = 0; nb < 4; nb++)
#pragma unroll
                    for (int jj = 0; jj < 4; jj++)
                        c2[nb][jj] = __builtin_amdgcn_mfma_f32_16x16x32_bf16(
                            af2[nb], bf2[p * 4 + jj][mk], c2[nb][jj], 0, 0, 0);
            }
#pragma unroll
            for (int nb = 0; nb < 4; nb++) {
                int n = h * 64 + nb * 16 + quad * 4;
#pragma unroll
                for (int jj = 0; jj < 4; jj++) {
                    int d = dstrip + p * 64 + jj * 16 + l15;
#pragma unroll
                    for (int rr = 0; rr < 4; rr++)
                        unsafeAtomicAdd(&xsa[xbase + (size_t)(n + rr) * D_ + d],
                                        c2[nb][jj][rr]);
                }
            }
        }
    }
}

// ---------------------------------------------------------------------------
// K4: per-expert linear (HBM-bound on W). Staging sums the NSL xs slices and
// normalizes by colsum. Bias add + fused bf16 transpose store ysT[b][e][n].
__global__ __launch_bounds__(256) void k_ys(const float* __restrict__ xsa,
                                            const float* __restrict__ colsum,
                                            const float* __restrict__ W,
                                            const float* __restrict__ bias,
                                            short* __restrict__ ysT) {
    __shared__ float xsn[B_][D_];
    int bi = blockIdx.x;
    int n = bi >> 2, eq = bi & 3;
    int tid = threadIdx.x;
    {
        int lb = tid >> 6, ld = (tid & 63) * 8;
        float inv = 1.0f / colsum[lb * N_ + n];
        size_t base = ((size_t)lb * N_ + n) * D_ + ld;
        float s0 = 0, s1 = 0, s2 = 0, s3 = 0, s4 = 0, s5 = 0, s6 = 0, s7 = 0;
#pragma unroll
        for (int s = 0; s < NSL; s++) {
            const float* p = &xsa[(size_t)s * (B_ * N_ * D_) + base];
            float4 v0 = *(const float4*)p;
            float4 v1 = *(const float4*)(p + 4);
            s0 += v0.x; s1 += v0.y; s2 += v0.z; s3 += v0.w;
            s4 += v1.x; s5 += v1.y; s6 += v1.z; s7 += v1.w;
        }
        float4 o0 = {s0 * inv, s1 * inv, s2 * inv, s3 * inv};
        float4 o1 = {s4 * inv, s5 * inv, s6 * inv, s7 * inv};
        *(float4*)&xsn[lb][ld] = o0;
        *(float4*)&xsn[lb][ld + 4] = o1;
    }
    __syncthreads();
    int b = tid >> 6;
    int e = eq * 128 + (tid & 63) * 2;
    const float* Wn = W + (size_t)n * D_ * D_ + e;
    float a0 = 0.f, a1 = 0.f;
#pragma unroll 8
    for (int d = 0; d < D_; d++) {
        float2 w = *(const float2*)&Wn[(size_t)d * D_];
        float xv = xsn[b][d];
        a0 += xv * w.x;
        a1 += xv * w.y;
    }
    float2 bv = *(const float2*)&bias[n * D_ + e];
    ysT[((size_t)b * D_ + e) * N_ + n] = f2bf(a0 + bv.x);
    ysT[((size_t)b * D_ + e + 1) * N_ + n] = f2bf(a1 + bv.y);
}

// ---------------------------------------------------------------------------
// K5: combine via bf16 MFMA. Block: 128m x 128d, K=n=128 in 4 chunks of 32.
// XCD-swizzled so the 4 dt-siblings re-reading the same E rows share an L2.
__global__ __launch_bounds__(256) void k_combine(const float* __restrict__ E,
                                                 const short* __restrict__ ysT,
                                                 float* __restrict__ y) {
    __shared__ short As[128 * 40];  // [m][n-chunk 0..31]
    __shared__ short Bs[128 * 40];  // [d][n-chunk 0..31]
    __shared__ float rsA[2][128];
    __shared__ float rsinv[128];
    int t = threadIdx.x;
    int bid = blockIdx.x;
    int bi = (bid & 7) * 128 + (bid >> 3);  // 1024 blocks, 8 XCDs, chunk=128
    int dt = bi & 3, mt = bi >> 2;
    int r0 = mt * 128, d0 = dt * 128;
    int bb = r0 >> 13;
    int sm = t >> 1, nh = (t & 1) * 16;
    const float* erow = &E[(size_t)(r0 + sm) * N_ + nh];
    const short* yrow = &ysT[((size_t)bb * D_ + d0 + sm) * N_ + nh];
    int wid = t >> 6, lane = t & 63;
    int quad = lane >> 4, l15 = lane & 15;
    int mw = (wid >> 1) * 64, dw = (wid & 1) * 64;
    f32x4 acc[4][4] = {};
    float rsp = 0.f;

    for (int ks = 0; ks < 4; ks++) {
        int n0 = ks * 32;
        float4 e0 = *(const float4*)&erow[n0];
        float4 e1 = *(const float4*)&erow[n0 + 4];
        float4 e2 = *(const float4*)&erow[n0 + 8];
        float4 e3 = *(const float4*)&erow[n0 + 12];
        rsp += e0.x + e0.y + e0.z + e0.w + e1.x + e1.y + e1.z + e1.w +
               e2.x + e2.y + e2.z + e2.w + e3.x + e3.y + e3.z + e3.w;
        short4 w0 = {f2bf(e0.x), f2bf(e0.y), f2bf(e0.z), f2bf(e0.w)};
        short4 w1 = {f2bf(e1.x), f2bf(e1.y), f2bf(e1.z), f2bf(e1.w)};
        short4 w2 = {f2bf(e2.x), f2bf(e2.y), f2bf(e2.z), f2bf(e2.w)};
        short4 w3 = {f2bf(e3.x), f2bf(e3.y), f2bf(e3.z), f2bf(e3.w)};
        *(short4*)&As[sm * 40 + nh + 0] = w0;
        *(short4*)&As[sm * 40 + nh + 4] = w1;
        *(short4*)&As[sm * 40 + nh + 8] = w2;
        *(short4*)&As[sm * 40 + nh + 12] = w3;
        *(s16x8*)&Bs[sm * 40 + nh] = *(const s16x8*)&yrow[n0];
        *(s16x8*)&Bs[sm * 40 + nh + 8] = *(const s16x8*)&yrow[n0 + 8];
        __syncthreads();
        s16x8 af[4], bf[4];
#pragma unroll
        for (int i = 0; i < 4; i++)
            af[i] = *(const s16x8*)&As[(mw + i * 16 + l15) * 40 + quad * 8];
#pragma unroll
        for (int j = 0; j < 4; j++)
            bf[j] = *(const s16x8*)&Bs[(dw + j * 16 + l15) * 40 + quad * 8];
#pragma unroll
        for (int i = 0; i < 4; i++)
#pragma unroll
            for (int j = 0; j < 4; j++)
                acc[i][j] = __builtin_amdgcn_mfma_f32_16x16x32_bf16(af[i], bf[j], acc[i][j], 0, 0, 0);
        __syncthreads();
    }
    rsA[t & 1][sm] = rsp;
    __syncthreads();
    if (t < 128) rsinv[t] = 1.0f / (rsA[0][t] + rsA[1][t]);
    __syncthreads();
#pragma unroll
    for (int i = 0; i < 4; i++) {
        int mb = mw + i * 16 + quad * 4;
        float i0 = rsinv[mb], i1 = rsinv[mb + 1], i2 = rsinv[mb + 2], i3 = rsinv[mb + 3];
#pragma unroll
        for (int j = 0; j < 4; j++) {
            int d = d0 + dw + j * 16 + l15;
            f32x4 v = acc[i][j];
            y[(size_t)(r0 + mb + 0) * D_ + d] = v[0] * i0;
            y[(size_t)(r0 + mb + 1) * D_ + d] = v[1] * i1;
            y[(size_t)(r0 + mb + 2) * D_ + d] = v[2] * i2;
            y[(size_t)(r0 + mb + 3) * D_ + d] = v[3] * i3;
        }
    }
}

// ---------------------------------------------------------------------------
extern "C" void kernel_launch(void* const* d_in, const int* in_sizes, int n_in,
                              void* d_out, int out_size, void* d_ws, size_t ws_size,
                              hipStream_t stream) {
    const float* x = (const float*)d_in[0];
    const float* phi = (const float*)d_in[1];
    const float* scale = (const float*)d_in[2];
    const float* W = (const float*)d_in[3];
    const float* bias = (const float*)d_in[4];
    float* y = (float*)d_out;
    float* ws = (float*)d_ws;

    float* colsum = ws + OFF_CS;
    float* xsa = ws + OFF_XSA;
    short* pbt = (short*)(ws + OFF_PBT);
    float* E = ws + OFF_E;
    short* ysT = (short*)(ws + OFF_YST);

    // zero colsum + xsa in one contiguous memset
    hipMemsetAsync(colsum, 0, (size_t)(512 + NSL * B_ * N_ * D_) * sizeof(float), stream);

    k_phinorm<<<N_, 128, 0, stream>>>(phi, scale, pbt);
    k_logits<<<TOK / 64, 256, 0, stream>>>(x, pbt, E, colsum, xsa);
    k_ys<<<N_ * 4, 256, 0, stream>>>(xsa, colsum, W, bias, ysT);
    k_combine<<<(TOK / 128) * 4, 256, 0, stream>>>(E, ysT, y);
}

// Round 4
// 325.914 us; speedup vs baseline: 1.2972x; 1.2972x over previous
//
#include <hip/hip_runtime.h>
#include <math.h>

// Problem constants: B=4, M=8192, D=512, N=128, P=1
#define B_ 4
#define M_ 8192
#define D_ 512
#define N_ 128
#define TOK (B_ * M_)    // 32768
#define MC_ 16           // split-K chunks over M for xs
#define MLEN (M_ / MC_)  // 512 rows per chunk

// Workspace layout (float offsets)
#define OFF_CS 0                                   // [512] colsum of raw exp
#define OFF_PBT (OFF_CS + 512)                     // [N*D] bf16 phi^T (shorts)
#define OFF_E (OFF_PBT + N_ * D_ / 2)              // [TOK*N] raw exp(logits) fp32
#define OFF_YST (OFF_E + (size_t)TOK * N_)         // [B*D*N] bf16 ys^T (shorts)
#define OFF_XBT (OFF_YST + B_ * D_ * N_ / 2)       // [D][TOK] bf16 raw-x^T (shorts)
#define OFF_EWT (OFF_XBT + (size_t)D_ * TOK / 2)   // [N][TOK] bf16 (E*rn)^T (shorts)
#define OFF_XP (OFF_EWT + (size_t)N_ * TOK / 2)    // [MC*B*N*D] fp32 partials

typedef __attribute__((ext_vector_type(8))) short s16x8;
typedef __attribute__((ext_vector_type(4))) float f32x4;

__device__ inline short f2bf(float f) {  // RNE round to bf16
    union { float f; unsigned u; } v;
    v.f = f;
    unsigned r = v.u + 0x7fffu + ((v.u >> 16) & 1u);
    return (short)(r >> 16);
}

// ---------------------------------------------------------------------------
// K0: phi col-normalize -> pbt[n][d] bf16 = scale * phi[d][n]/max(||phi[:,n]||,eps)
__global__ __launch_bounds__(128) void k_phinorm(const float* __restrict__ phi,
                                                 const float* __restrict__ scale,
                                                 short* __restrict__ pbt) {
    __shared__ float sred[128];
    int n = blockIdx.x, tid = threadIdx.x;
    float ss = 0.f;
    for (int d = tid; d < D_; d += 128) {
        float v = phi[d * N_ + n];
        ss += v * v;
    }
    sred[tid] = ss;
    __syncthreads();
    for (int s = 64; s > 0; s >>= 1) {
        if (tid < s) sred[tid] += sred[tid + s];
        __syncthreads();
    }
    float sc = scale[0] / fmaxf(sqrtf(sred[0]), 1e-12f);
    for (int d = tid; d < D_; d += 128) pbt[n * D_ + d] = f2bf(phi[d * N_ + n] * sc);
}

// ---------------------------------------------------------------------------
// K1: logits. 128m x 128n tile, 512 thr (8 waves, 4x2). Double-buffered LDS,
// ONE barrier per K-step, next-step global loads issued before the MFMAs.
// MFMA on raw bf16(x) (rn applied in epilogue). Per K-step also transpose-
// writes the As tile to xbt[d][m]. Emits E fp32, ewt = bf16(E*rn)^T, colsum.
__global__ __launch_bounds__(512) void k_logits(const float* __restrict__ x,
                                                const short* __restrict__ pbt,
                                                float* __restrict__ E,
                                                short* __restrict__ ewt,
                                                short* __restrict__ xbt,
                                                float* __restrict__ colsum) {
    __shared__ short As[2][128 * 40];
    __shared__ short Bs[2][128 * 40];
    __shared__ float rnS[128];
    short* T = &As[0][0];  // epilogue overlay: 64 x 136 shorts (8704 <= 10240)

    int t = threadIdx.x;
    int r0 = blockIdx.x * 128;
    int sm = t >> 2;           // staging row (m for A, n for B)
    int kq = (t & 3) * 8;      // k sub-chunk
    const float* xrow = &x[(size_t)(r0 + sm) * D_ + kq];
    const short* brow = &pbt[sm * D_ + kq];
    int wid = t >> 6, lane = t & 63;
    int quad = lane >> 4, l15 = lane & 15;
    int mw = (wid >> 1) * 32, nw = (wid & 1) * 64;
    int dl = t & 31, mg = t >> 5;  // xbt transpose mapping: 32 d x 16 m-groups
    f32x4 acc[2][4] = {};
    float ss = 0.f;

    {  // prologue: stage k-step 0
        float4 a0 = *(const float4*)&xrow[0];
        float4 a1 = *(const float4*)&xrow[4];
        s16x8 bv = *(const s16x8*)&brow[0];
        ss += a0.x * a0.x + a0.y * a0.y + a0.z * a0.z + a0.w * a0.w +
              a1.x * a1.x + a1.y * a1.y + a1.z * a1.z + a1.w * a1.w;
        s16x8 av;
        av[0] = f2bf(a0.x); av[1] = f2bf(a0.y); av[2] = f2bf(a0.z); av[3] = f2bf(a0.w);
        av[4] = f2bf(a1.x); av[5] = f2bf(a1.y); av[6] = f2bf(a1.z); av[7] = f2bf(a1.w);
        *(s16x8*)&As[0][sm * 40 + kq] = av;
        *(s16x8*)&Bs[0][sm * 40 + kq] = bv;
    }
    __syncthreads();

#pragma unroll
    for (int kt = 0; kt < 16; kt++) {
        int cur = kt & 1;
        float4 na0, na1;
        s16x8 nbv;
        if (kt < 15) {  // issue next-step loads; in flight under MFMA
            na0 = *(const float4*)&xrow[(kt + 1) * 32];
            na1 = *(const float4*)&xrow[(kt + 1) * 32 + 4];
            nbv = *(const s16x8*)&brow[(kt + 1) * 32];
        }
        s16x8 af[2], bfr[4];
#pragma unroll
        for (int i = 0; i < 2; i++)
            af[i] = *(const s16x8*)&As[cur][(mw + i * 16 + l15) * 40 + quad * 8];
#pragma unroll
        for (int j = 0; j < 4; j++)
            bfr[j] = *(const s16x8*)&Bs[cur][(nw + j * 16 + l15) * 40 + quad * 8];
#pragma unroll
        for (int i = 0; i < 2; i++)
#pragma unroll
            for (int j = 0; j < 4; j++)
                acc[i][j] = __builtin_amdgcn_mfma_f32_16x16x32_bf16(af[i], bfr[j], acc[i][j], 0, 0, 0);
        {  // transpose-write raw-x tile to xbt[d][m]
            s16x8 tv;
#pragma unroll
            for (int r = 0; r < 8; r++) tv[r] = As[cur][(mg * 8 + r) * 40 + dl];
            *(s16x8*)&xbt[(size_t)(kt * 32 + dl) * TOK + r0 + mg * 8] = tv;
        }
        if (kt < 15) {  // convert + stage into other buffer
            ss += na0.x * na0.x + na0.y * na0.y + na0.z * na0.z + na0.w * na0.w +
                  na1.x * na1.x + na1.y * na1.y + na1.z * na1.z + na1.w * na1.w;
            s16x8 nav;
            nav[0] = f2bf(na0.x); nav[1] = f2bf(na0.y); nav[2] = f2bf(na0.z); nav[3] = f2bf(na0.w);
            nav[4] = f2bf(na1.x); nav[5] = f2bf(na1.y); nav[6] = f2bf(na1.z); nav[7] = f2bf(na1.w);
            *(s16x8*)&As[cur ^ 1][sm * 40 + kq] = nav;
            *(s16x8*)&Bs[cur ^ 1][sm * 40 + kq] = nbv;
        }
        __syncthreads();
    }
    // row inverse norms: 4 consecutive lanes share a row
    ss += __shfl_xor(ss, 1, 64);
    ss += __shfl_xor(ss, 2, 64);
    if ((t & 3) == 0) rnS[sm] = 1.0f / fmaxf(sqrtf(ss), 1e-12f);
    __syncthreads();

    int bb = r0 >> 13;
    float rv[2][4];
#pragma unroll
    for (int i = 0; i < 2; i++) {
        int ml = mw + i * 16 + quad * 4;
        rv[i][0] = rnS[ml]; rv[i][1] = rnS[ml + 1];
        rv[i][2] = rnS[ml + 2]; rv[i][3] = rnS[ml + 3];
    }
    short4 ebf[2][4];
#pragma unroll
    for (int j = 0; j < 4; j++) {
        int n = nw + j * 16 + l15;
        float cs = 0.f;
#pragma unroll
        for (int i = 0; i < 2; i++) {
            int mb = r0 + mw + i * 16 + quad * 4;
            f32x4 vv = acc[i][j];
            float e0 = __expf(vv[0] * rv[i][0]), e1 = __expf(vv[1] * rv[i][1]);
            float e2 = __expf(vv[2] * rv[i][2]), e3 = __expf(vv[3] * rv[i][3]);
            cs += e0 + e1 + e2 + e3;
            E[(size_t)(mb + 0) * N_ + n] = e0;
            E[(size_t)(mb + 1) * N_ + n] = e1;
            E[(size_t)(mb + 2) * N_ + n] = e2;
            E[(size_t)(mb + 3) * N_ + n] = e3;
            short4 eb = {f2bf(e0 * rv[i][0]), f2bf(e1 * rv[i][1]),
                         f2bf(e2 * rv[i][2]), f2bf(e3 * rv[i][3])};
            ebf[i][j] = eb;
        }
        cs += __shfl_xor(cs, 16, 64);
        cs += __shfl_xor(cs, 32, 64);
        if (lane < 16) atomicAdd(&colsum[bb * N_ + n], cs);
    }
    // ewt[n][r0..r0+127] = bf16(E*rn) via LDS transpose, two 64-row n-halves
#pragma unroll
    for (int h = 0; h < 2; h++) {
        if ((wid & 1) == h) {
#pragma unroll
            for (int i = 0; i < 2; i++) {
                int mb = mw + i * 16 + quad * 4;  // local m 0..127
#pragma unroll
                for (int j = 0; j < 4; j++) {
                    int nl = j * 16 + l15;       // local n within half 0..63
                    *(short4*)&T[nl * 136 + mb] = ebf[i][j];
                }
            }
        }
        __syncthreads();
        {
            int nl = t >> 3, c = t & 7;
            s16x8 v0 = *(const s16x8*)&T[nl * 136 + c * 16];
            s16x8 v1 = *(const s16x8*)&T[nl * 136 + c * 16 + 8];
            size_t go = (size_t)(h * 64 + nl) * TOK + r0 + c * 16;
            *(s16x8*)&ewt[go] = v0;
            *(s16x8*)&ewt[go + 8] = v1;
        }
        __syncthreads();
    }
}

// ---------------------------------------------------------------------------
// K3: xs partials via bf16 MFMA. part[mc][b][n][d] = sum_m ewt[n][m]*xbt[d][m].
// 512 thr (8 waves = 2/SIMD), tile 128n x 128d, K=512 m. Double-buffered LDS,
// one barrier per K-step, loads prefetched under MFMA. XCD-swizzled grid.
__global__ __launch_bounds__(512) void k_xs(const short* __restrict__ ewt,
                                            const short* __restrict__ xbt,
                                            float* __restrict__ part) {
    __shared__ short An[2][128 * 40];  // [n][k-chunk 0..31]
    __shared__ short Bd[2][128 * 40];  // [d][k-chunk 0..31]
    int t = threadIdx.x;
    int bid = blockIdx.x;
    int bi = (bid & 7) * 32 + (bid >> 3);  // 256 blocks, 8 XCDs, chunk=32
    int dt = bi & 3, mc = (bi >> 2) & 15, b = bi >> 6;
    int d0 = dt * 128;
    size_t mbase = (size_t)b * M_ + (size_t)mc * MLEN;
    int rs = t >> 2, kq = (t & 3) * 8;
    const short* arow = &ewt[(size_t)rs * TOK + mbase + kq];
    const short* brow = &xbt[(size_t)(d0 + rs) * TOK + mbase + kq];
    int wid = t >> 6, lane = t & 63;
    int quad = lane >> 4, l15 = lane & 15;
    int nw = (wid >> 2) * 64, dw = (wid & 3) * 32;
    f32x4 acc[4][2] = {};

    {
        s16x8 ra = *(const s16x8*)&arow[0];
        s16x8 rb = *(const s16x8*)&brow[0];
        *(s16x8*)&An[0][rs * 40 + kq] = ra;
        *(s16x8*)&Bd[0][rs * 40 + kq] = rb;
    }
    __syncthreads();

#pragma unroll
    for (int kt = 0; kt < 16; kt++) {
        int cur = kt & 1;
        s16x8 ra, rb;
        if (kt < 15) {
            ra = *(const s16x8*)&arow[(kt + 1) * 32];
            rb = *(const s16x8*)&brow[(kt + 1) * 32];
        }
        s16x8 af[4], bf[2];
#pragma unroll
        for (int i = 0; i < 4; i++)
            af[i] = *(const s16x8*)&An[cur][(nw + i * 16 + l15) * 40 + quad * 8];
#pragma unroll
        for (int j = 0; j < 2; j++)
            bf[j] = *(const s16x8*)&Bd[cur][(dw + j * 16 + l15) * 40 + quad * 8];
#pragma unroll
        for (int i = 0; i < 4; i++)
#pragma unroll
            for (int j = 0; j < 2; j++)
                acc[i][j] = __builtin_amdgcn_mfma_f32_16x16x32_bf16(af[i], bf[j], acc[i][j], 0, 0, 0);
        if (kt < 15) {
            *(s16x8*)&An[cur ^ 1][rs * 40 + kq] = ra;
            *(s16x8*)&Bd[cur ^ 1][rs * 40 + kq] = rb;
        }
        __syncthreads();
    }
    size_t pbase = (((size_t)mc * B_ + b) * N_) * D_ + d0;
#pragma unroll
    for (int i = 0; i < 4; i++) {
        int nb = nw + i * 16 + quad * 4;
#pragma unroll
        for (int j = 0; j < 2; j++) {
            int d = dw + j * 16 + l15;
            f32x4 vv = acc[i][j];
            part[pbase + (size_t)(nb + 0) * D_ + d] = vv[0];
            part[pbase + (size_t)(nb + 1) * D_ + d] = vv[1];
            part[pbase + (size_t)(nb + 2) * D_ + d] = vv[2];
            part[pbase + (size_t)(nb + 3) * D_ + d] = vv[3];
        }
    }
}

// ---------------------------------------------------------------------------
// K4: per-expert linear (HBM-bound on W). Staging reduces the MC partials and
// normalizes by colsum (k_xsum folded in). Bias + fused bf16 transpose store.
__global__ __launch_bounds__(256) void k_ys(const float* __restrict__ part,
                                            const float* __restrict__ colsum,
                                            const float* __restrict__ W,
                                            const float* __restrict__ bias,
                                            short* __restrict__ ysT) {
    __shared__ float xsn[B_][D_];
    int bi = blockIdx.x;
    int n = bi >> 2, eq = bi & 3;
    int tid = threadIdx.x;
    {
        int lb = tid >> 6, ld = (tid & 63) * 8;
        float inv = 1.0f / colsum[lb * N_ + n];
        float s0 = 0, s1 = 0, s2 = 0, s3 = 0, s4 = 0, s5 = 0, s6 = 0, s7 = 0;
#pragma unroll
        for (int mc = 0; mc < MC_; mc++) {
            const float* p = &part[(((size_t)mc * B_ + lb) * N_ + n) * D_ + ld];
            float4 v0 = *(const float4*)p;
            float4 v1 = *(const float4*)(p + 4);
            s0 += v0.x; s1 += v0.y; s2 += v0.z; s3 += v0.w;
            s4 += v1.x; s5 += v1.y; s6 += v1.z; s7 += v1.w;
        }
        float4 o0 = {s0 * inv, s1 * inv, s2 * inv, s3 * inv};
        float4 o1 = {s4 * inv, s5 * inv, s6 * inv, s7 * inv};
        *(float4*)&xsn[lb][ld] = o0;
        *(float4*)&xsn[lb][ld + 4] = o1;
    }
    __syncthreads();
    int b = tid >> 6;
    int e = eq * 128 + (tid & 63) * 2;
    const float* Wn = W + (size_t)n * D_ * D_ + e;
    float a0 = 0.f, a1 = 0.f;
#pragma unroll 8
    for (int d = 0; d < D_; d++) {
        float2 w = *(const float2*)&Wn[(size_t)d * D_];
        float xv = xsn[b][d];
        a0 += xv * w.x;
        a1 += xv * w.y;
    }
    float2 bv = *(const float2*)&bias[n * D_ + e];
    ysT[((size_t)b * D_ + e) * N_ + n] = f2bf(a0 + bv.x);
    ysT[((size_t)b * D_ + e + 1) * N_ + n] = f2bf(a1 + bv.y);
}

// ---------------------------------------------------------------------------
// K5: combine via bf16 MFMA. Block: 128m x 128d, K=n=128 in 4 chunks of 32.
// XCD-swizzled so the 4 dt-siblings re-reading the same E rows share an L2.
__global__ __launch_bounds__(256) void k_combine(const float* __restrict__ E,
                                                 const short* __restrict__ ysT,
                                                 float* __restrict__ y) {
    __shared__ short As[128 * 40];  // [m][n-chunk 0..31]
    __shared__ short Bs[128 * 40];  // [d][n-chunk 0..31]
    __shared__ float rsA[2][128];
    __shared__ float rsinv[128];
    int t = threadIdx.x;
    int bid = blockIdx.x;
    int bi = (bid & 7) * 128 + (bid >> 3);  // 1024 blocks, 8 XCDs, chunk=128
    int dt = bi & 3, mt = bi >> 2;
    int r0 = mt * 128, d0 = dt * 128;
    int bb = r0 >> 13;
    int sm = t >> 1, nh = (t & 1) * 16;
    const float* erow = &E[(size_t)(r0 + sm) * N_ + nh];
    const short* yrow = &ysT[((size_t)bb * D_ + d0 + sm) * N_ + nh];
    int wid = t >> 6, lane = t & 63;
    int quad = lane >> 4, l15 = lane & 15;
    int mw = (wid >> 1) * 64, dw = (wid & 1) * 64;
    f32x4 acc[4][4] = {};
    float rsp = 0.f;

    for (int ks = 0; ks < 4; ks++) {
        int n0 = ks * 32;
        float4 e0 = *(const float4*)&erow[n0];
        float4 e1 = *(const float4*)&erow[n0 + 4];
        float4 e2 = *(const float4*)&erow[n0 + 8];
        float4 e3 = *(const float4*)&erow[n0 + 12];
        rsp += e0.x + e0.y + e0.z + e0.w + e1.x + e1.y + e1.z + e1.w +
               e2.x + e2.y + e2.z + e2.w + e3.x + e3.y + e3.z + e3.w;
        short4 w0 = {f2bf(e0.x), f2bf(e0.y), f2bf(e0.z), f2bf(e0.w)};
        short4 w1 = {f2bf(e1.x), f2bf(e1.y), f2bf(e1.z), f2bf(e1.w)};
        short4 w2 = {f2bf(e2.x), f2bf(e2.y), f2bf(e2.z), f2bf(e2.w)};
        short4 w3 = {f2bf(e3.x), f2bf(e3.y), f2bf(e3.z), f2bf(e3.w)};
        *(short4*)&As[sm * 40 + nh + 0] = w0;
        *(short4*)&As[sm * 40 + nh + 4] = w1;
        *(short4*)&As[sm * 40 + nh + 8] = w2;
        *(short4*)&As[sm * 40 + nh + 12] = w3;
        *(s16x8*)&Bs[sm * 40 + nh] = *(const s16x8*)&yrow[n0];
        *(s16x8*)&Bs[sm * 40 + nh + 8] = *(const s16x8*)&yrow[n0 + 8];
        __syncthreads();
        s16x8 af[4], bf[4];
#pragma unroll
        for (int i = 0; i < 4; i++)
            af[i] = *(const s16x8*)&As[(mw + i * 16 + l15) * 40 + quad * 8];
#pragma unroll
        for (int j = 0; j < 4; j++)
            bf[j] = *(const s16x8*)&Bs[(dw + j * 16 + l15) * 40 + quad * 8];
#pragma unroll
        for (int i = 0; i < 4; i++)
#pragma unroll
            for (int j = 0; j < 4; j++)
                acc[i][j] = __builtin_amdgcn_mfma_f32_16x16x32_bf16(af[i], bf[j], acc[i][j], 0, 0, 0);
        __syncthreads();
    }
    rsA[t & 1][sm] = rsp;
    __syncthreads();
    if (t < 128) rsinv[t] = 1.0f / (rsA[0][t] + rsA[1][t]);
    __syncthreads();
#pragma unroll
    for (int i = 0; i < 4; i++) {
        int mb = mw + i * 16 + quad * 4;
        float i0 = rsinv[mb], i1 = rsinv[mb + 1], i2 = rsinv[mb + 2], i3 = rsinv[mb + 3];
#pragma unroll
        for (int j = 0; j < 4; j++) {
            int d = d0 + dw + j * 16 + l15;
            f32x4 v = acc[i][j];
            y[(size_t)(r0 + mb + 0) * D_ + d] = v[0] * i0;
            y[(size_t)(r0 + mb + 1) * D_ + d] = v[1] * i1;
            y[(size_t)(r0 + mb + 2) * D_ + d] = v[2] * i2;
            y[(size_t)(r0 + mb + 3) * D_ + d] = v[3] * i3;
        }
    }
}

// ---------------------------------------------------------------------------
extern "C" void kernel_launch(void* const* d_in, const int* in_sizes, int n_in,
                              void* d_out, int out_size, void* d_ws, size_t ws_size,
                              hipStream_t stream) {
    const float* x = (const float*)d_in[0];
    const float* phi = (const float*)d_in[1];
    const float* scale = (const float*)d_in[2];
    const float* W = (const float*)d_in[3];
    const float* bias = (const float*)d_in[4];
    float* y = (float*)d_out;
    float* ws = (float*)d_ws;

    float* colsum = ws + OFF_CS;
    short* pbt = (short*)(ws + OFF_PBT);
    float* E = ws + OFF_E;
    short* ysT = (short*)(ws + OFF_YST);
    short* xbt = (short*)(ws + OFF_XBT);
    short* ewt = (short*)(ws + OFF_EWT);
    float* part = ws + OFF_XP;

    hipMemsetAsync(colsum, 0, 512 * sizeof(float), stream);

    k_phinorm<<<N_, 128, 0, stream>>>(phi, scale, pbt);
    k_logits<<<TOK / 128, 512, 0, stream>>>(x, pbt, E, ewt, xbt, colsum);
    k_xs<<<B_ * MC_ * 4, 512, 0, stream>>>(ewt, xbt, part);
    k_ys<<<N_ * 4, 256, 0, stream>>>(part, colsum, W, bias, ysT);
    k_combine<<<(TOK / 128) * 4, 256, 0, stream>>>(E, ysT, y);
}

// Round 5
// 311.020 us; speedup vs baseline: 1.3593x; 1.0479x over previous
//
#include <hip/hip_runtime.h>
#include <math.h>

// Problem constants: B=4, M=8192, D=512, N=128, P=1
#define B_ 4
#define M_ 8192
#define D_ 512
#define N_ 128
#define TOK (B_ * M_)    // 32768
#define MC_ 16           // split-K chunks over M for xs
#define MLEN (M_ / MC_)  // 512 rows per chunk

// Workspace layout (float offsets)
#define OFF_CS 0                                   // [512] colsum of raw exp
#define OFF_PBT (OFF_CS + 512)                     // [N*D] bf16 phi^T (shorts)
#define OFF_EBN (OFF_PBT + N_ * D_ / 2)            // [TOK][N] bf16 E/rowsum (shorts)
#define OFF_EWT (OFF_EBN + (size_t)TOK * N_ / 2)   // [N][TOK] bf16 (E*rn)^T (shorts)
#define OFF_XBT (OFF_EWT + (size_t)N_ * TOK / 2)   // [D][TOK] bf16 raw-x^T (shorts)
#define OFF_YST (OFF_XBT + (size_t)D_ * TOK / 2)   // [B*D*N] bf16 ys^T (shorts)
#define OFF_XP (OFF_YST + B_ * D_ * N_ / 2)        // [MC*B*N*D] fp32 partials

typedef __attribute__((ext_vector_type(8))) short s16x8;
typedef __attribute__((ext_vector_type(4))) float f32x4;

__device__ inline short f2bf(float f) {  // RNE round to bf16
    union { float f; unsigned u; } v;
    v.f = f;
    unsigned r = v.u + 0x7fffu + ((v.u >> 16) & 1u);
    return (short)(r >> 16);
}

// ---------------------------------------------------------------------------
// K0: phi col-normalize -> pbt[n][d] bf16 = scale * phi[d][n]/max(||phi[:,n]||,eps)
__global__ __launch_bounds__(128) void k_phinorm(const float* __restrict__ phi,
                                                 const float* __restrict__ scale,
                                                 short* __restrict__ pbt) {
    __shared__ float sred[128];
    int n = blockIdx.x, tid = threadIdx.x;
    float ss = 0.f;
    for (int d = tid; d < D_; d += 128) {
        float v = phi[d * N_ + n];
        ss += v * v;
    }
    sred[tid] = ss;
    __syncthreads();
    for (int s = 64; s > 0; s >>= 1) {
        if (tid < s) sred[tid] += sred[tid + s];
        __syncthreads();
    }
    float sc = scale[0] / fmaxf(sqrtf(sred[0]), 1e-12f);
    for (int d = tid; d < D_; d += 128) pbt[n * D_ + d] = f2bf(phi[d * N_ + n] * sc);
}

// ---------------------------------------------------------------------------
// K1: logits. 128m x 128n tile, 512 thr (8 waves, 4x2). Double-buffered LDS,
// one barrier per K-step, next-step loads issued before the MFMAs. MFMA on
// raw bf16(x); rn applied in epilogue. Per K-step transpose-writes As tile to
// xbt[d][m]. Epilogue: rowsum in-block -> ebn[m][n]=bf16(E/rowsum) (coalesced,
// LDS-staged); ewt[n][m]=bf16(E*rn); colsum atomics. No fp32 E anywhere.
__global__ __launch_bounds__(512) void k_logits(const float* __restrict__ x,
                                                const short* __restrict__ pbt,
                                                short* __restrict__ ebn,
                                                short* __restrict__ ewt,
                                                short* __restrict__ xbt,
                                                float* __restrict__ colsum) {
    __shared__ short smem[4 * 128 * 40];  // As dbuf | Bs dbuf; T/T2 overlay after loop
    __shared__ float rnS[128];
    __shared__ float rsH[2][128];

    int t = threadIdx.x;
    int r0 = blockIdx.x * 128;
    int sm = t >> 2;           // staging row (m for A, n for B)
    int kq = (t & 3) * 8;      // k sub-chunk
    const float* xrow = &x[(size_t)(r0 + sm) * D_ + kq];
    const short* brow = &pbt[sm * D_ + kq];
    int wid = t >> 6, lane = t & 63;
    int quad = lane >> 4, l15 = lane & 15;
    int mw = (wid >> 1) * 32, nw = (wid & 1) * 64;
    int dl = t & 31, mg = t >> 5;  // xbt transpose mapping: 32 d x 16 m-groups
    f32x4 acc[2][4] = {};
    float ss = 0.f;

    {  // prologue: stage k-step 0
        float4 a0 = *(const float4*)&xrow[0];
        float4 a1 = *(const float4*)&xrow[4];
        s16x8 bv = *(const s16x8*)&brow[0];
        ss += a0.x * a0.x + a0.y * a0.y + a0.z * a0.z + a0.w * a0.w +
              a1.x * a1.x + a1.y * a1.y + a1.z * a1.z + a1.w * a1.w;
        s16x8 av;
        av[0] = f2bf(a0.x); av[1] = f2bf(a0.y); av[2] = f2bf(a0.z); av[3] = f2bf(a0.w);
        av[4] = f2bf(a1.x); av[5] = f2bf(a1.y); av[6] = f2bf(a1.z); av[7] = f2bf(a1.w);
        *(s16x8*)&smem[0 * 5120 + sm * 40 + kq] = av;
        *(s16x8*)&smem[10240 + 0 * 5120 + sm * 40 + kq] = bv;
    }
    __syncthreads();

#pragma unroll
    for (int kt = 0; kt < 16; kt++) {
        int cur = kt & 1;
        short* As = &smem[cur * 5120];
        short* Bs = &smem[10240 + cur * 5120];
        float4 na0, na1;
        s16x8 nbv;
        if (kt < 15) {  // issue next-step loads; in flight under MFMA
            na0 = *(const float4*)&xrow[(kt + 1) * 32];
            na1 = *(const float4*)&xrow[(kt + 1) * 32 + 4];
            nbv = *(const s16x8*)&brow[(kt + 1) * 32];
        }
        s16x8 af[2], bfr[4];
#pragma unroll
        for (int i = 0; i < 2; i++)
            af[i] = *(const s16x8*)&As[(mw + i * 16 + l15) * 40 + quad * 8];
#pragma unroll
        for (int j = 0; j < 4; j++)
            bfr[j] = *(const s16x8*)&Bs[(nw + j * 16 + l15) * 40 + quad * 8];
#pragma unroll
        for (int i = 0; i < 2; i++)
#pragma unroll
            for (int j = 0; j < 4; j++)
                acc[i][j] = __builtin_amdgcn_mfma_f32_16x16x32_bf16(af[i], bfr[j], acc[i][j], 0, 0, 0);
        {  // transpose-write raw-x tile to xbt[d][m]
            s16x8 tv;
#pragma unroll
            for (int r = 0; r < 8; r++) tv[r] = As[(mg * 8 + r) * 40 + dl];
            *(s16x8*)&xbt[(size_t)(kt * 32 + dl) * TOK + r0 + mg * 8] = tv;
        }
        if (kt < 15) {  // convert + stage into other buffer
            ss += na0.x * na0.x + na0.y * na0.y + na0.z * na0.z + na0.w * na0.w +
                  na1.x * na1.x + na1.y * na1.y + na1.z * na1.z + na1.w * na1.w;
            s16x8 nav;
            nav[0] = f2bf(na0.x); nav[1] = f2bf(na0.y); nav[2] = f2bf(na0.z); nav[3] = f2bf(na0.w);
            nav[4] = f2bf(na1.x); nav[5] = f2bf(na1.y); nav[6] = f2bf(na1.z); nav[7] = f2bf(na1.w);
            *(s16x8*)&smem[(cur ^ 1) * 5120 + sm * 40 + kq] = nav;
            *(s16x8*)&smem[10240 + (cur ^ 1) * 5120 + sm * 40 + kq] = nbv;
        }
        __syncthreads();
    }
    // row inverse norms: 4 consecutive lanes share a row
    ss += __shfl_xor(ss, 1, 64);
    ss += __shfl_xor(ss, 2, 64);
    if ((t & 3) == 0) rnS[sm] = 1.0f / fmaxf(sqrtf(ss), 1e-12f);
    __syncthreads();

    int bb = r0 >> 13;
    float rv[2][4];
#pragma unroll
    for (int i = 0; i < 2; i++) {
        int ml = mw + i * 16 + quad * 4;
        rv[i][0] = rnS[ml]; rv[i][1] = rnS[ml + 1];
        rv[i][2] = rnS[ml + 2]; rv[i][3] = rnS[ml + 3];
    }
    // exp (raw, kept in acc), colsum atomics, per-row partial sums, ewt values
    float rs[2][4] = {};
    short4 ebf[2][4];
#pragma unroll
    for (int j = 0; j < 4; j++) {
        int n = nw + j * 16 + l15;
        float cs = 0.f;
#pragma unroll
        for (int i = 0; i < 2; i++) {
            f32x4 vv = acc[i][j];
            float e0 = __expf(vv[0] * rv[i][0]), e1 = __expf(vv[1] * rv[i][1]);
            float e2 = __expf(vv[2] * rv[i][2]), e3 = __expf(vv[3] * rv[i][3]);
            acc[i][j][0] = e0; acc[i][j][1] = e1; acc[i][j][2] = e2; acc[i][j][3] = e3;
            cs += e0 + e1 + e2 + e3;
            rs[i][0] += e0; rs[i][1] += e1; rs[i][2] += e2; rs[i][3] += e3;
            short4 eb = {f2bf(e0 * rv[i][0]), f2bf(e1 * rv[i][1]),
                         f2bf(e2 * rv[i][2]), f2bf(e3 * rv[i][3])};
            ebf[i][j] = eb;
        }
        cs += __shfl_xor(cs, 16, 64);
        cs += __shfl_xor(cs, 32, 64);
        if (lane < 16) atomicAdd(&colsum[bb * N_ + n], cs);
    }
    // rowsum: reduce over the 16 l15 lanes, combine the two n-half waves via LDS
#pragma unroll
    for (int off = 1; off <= 8; off <<= 1)
#pragma unroll
        for (int i = 0; i < 2; i++)
#pragma unroll
            for (int r = 0; r < 4; r++) rs[i][r] += __shfl_xor(rs[i][r], off, 64);
    if (l15 == 0) {
#pragma unroll
        for (int i = 0; i < 2; i++)
#pragma unroll
            for (int r = 0; r < 4; r++)
                rsH[wid & 1][mw + i * 16 + quad * 4 + r] = rs[i][r];
    }
    __syncthreads();
    float ri[2][4];
#pragma unroll
    for (int i = 0; i < 2; i++)
#pragma unroll
        for (int r = 0; r < 4; r++) {
            int m = mw + i * 16 + quad * 4 + r;
            ri[i][r] = 1.0f / (rsH[0][m] + rsH[1][m]);
        }

    // ewt[n][r0..r0+127] = bf16(E*rn) via LDS transpose, two 64-row n-halves
    short* T = smem;  // 64 x 136 shorts
#pragma unroll
    for (int h = 0; h < 2; h++) {
        if ((wid & 1) == h) {
#pragma unroll
            for (int i = 0; i < 2; i++) {
                int mb = mw + i * 16 + quad * 4;  // local m 0..127
#pragma unroll
                for (int j = 0; j < 4; j++) {
                    int nl = j * 16 + l15;       // local n within half 0..63
                    *(short4*)&T[nl * 136 + mb] = ebf[i][j];
                }
            }
        }
        __syncthreads();
        {
            int nl = t >> 3, c = t & 7;
            s16x8 v0 = *(const s16x8*)&T[nl * 136 + c * 16];
            s16x8 v1 = *(const s16x8*)&T[nl * 136 + c * 16 + 8];
            size_t go = (size_t)(h * 64 + nl) * TOK + r0 + c * 16;
            *(s16x8*)&ewt[go] = v0;
            *(s16x8*)&ewt[go + 8] = v1;
        }
        __syncthreads();
    }

    // ebn[m][n] = bf16(E/rowsum), staged in LDS -> fully coalesced stores
    short* T2 = smem;  // 128 x 136 shorts (34816 B <= 40960 B)
#pragma unroll
    for (int j = 0; j < 4; j++) {
        int n = nw + j * 16 + l15;
#pragma unroll
        for (int i = 0; i < 2; i++) {
            int m = mw + i * 16 + quad * 4;
            f32x4 vv = acc[i][j];
            T2[(m + 0) * 136 + n] = f2bf(vv[0] * ri[i][0]);
            T2[(m + 1) * 136 + n] = f2bf(vv[1] * ri[i][1]);
            T2[(m + 2) * 136 + n] = f2bf(vv[2] * ri[i][2]);
            T2[(m + 3) * 136 + n] = f2bf(vv[3] * ri[i][3]);
        }
    }
    __syncthreads();
    {
        int row = t >> 2, c = (t & 3) * 32;
        s16x8 v0 = *(const s16x8*)&T2[row * 136 + c];
        s16x8 v1 = *(const s16x8*)&T2[row * 136 + c + 8];
        s16x8 v2 = *(const s16x8*)&T2[row * 136 + c + 16];
        s16x8 v3 = *(const s16x8*)&T2[row * 136 + c + 24];
        size_t go = (size_t)(r0 + row) * N_ + c;
        *(s16x8*)&ebn[go] = v0;
        *(s16x8*)&ebn[go + 8] = v1;
        *(s16x8*)&ebn[go + 16] = v2;
        *(s16x8*)&ebn[go + 24] = v3;
    }
}

// ---------------------------------------------------------------------------
// K3: xs partials via bf16 MFMA. part[mc][b][n][d] = sum_m ewt[n][m]*xbt[d][m].
// 512 thr (8 waves = 2/SIMD), tile 128n x 128d, K=512 m. Double-buffered LDS,
// one barrier per K-step, loads prefetched under MFMA. XCD-swizzled grid.
__global__ __launch_bounds__(512) void k_xs(const short* __restrict__ ewt,
                                            const short* __restrict__ xbt,
                                            float* __restrict__ part) {
    __shared__ short An[2][128 * 40];  // [n][k-chunk 0..31]
    __shared__ short Bd[2][128 * 40];  // [d][k-chunk 0..31]
    int t = threadIdx.x;
    int bid = blockIdx.x;
    int bi = (bid & 7) * 32 + (bid >> 3);  // 256 blocks, 8 XCDs, chunk=32
    int dt = bi & 3, mc = (bi >> 2) & 15, b = bi >> 6;
    int d0 = dt * 128;
    size_t mbase = (size_t)b * M_ + (size_t)mc * MLEN;
    int rs = t >> 2, kq = (t & 3) * 8;
    const short* arow = &ewt[(size_t)rs * TOK + mbase + kq];
    const short* brow = &xbt[(size_t)(d0 + rs) * TOK + mbase + kq];
    int wid = t >> 6, lane = t & 63;
    int quad = lane >> 4, l15 = lane & 15;
    int nw = (wid >> 2) * 64, dw = (wid & 3) * 32;
    f32x4 acc[4][2] = {};

    {
        s16x8 ra = *(const s16x8*)&arow[0];
        s16x8 rb = *(const s16x8*)&brow[0];
        *(s16x8*)&An[0][rs * 40 + kq] = ra;
        *(s16x8*)&Bd[0][rs * 40 + kq] = rb;
    }
    __syncthreads();

#pragma unroll
    for (int kt = 0; kt < 16; kt++) {
        int cur = kt & 1;
        s16x8 ra, rb;
        if (kt < 15) {
            ra = *(const s16x8*)&arow[(kt + 1) * 32];
            rb = *(const s16x8*)&brow[(kt + 1) * 32];
        }
        s16x8 af[4], bf[2];
#pragma unroll
        for (int i = 0; i < 4; i++)
            af[i] = *(const s16x8*)&An[cur][(nw + i * 16 + l15) * 40 + quad * 8];
#pragma unroll
        for (int j = 0; j < 2; j++)
            bf[j] = *(const s16x8*)&Bd[cur][(dw + j * 16 + l15) * 40 + quad * 8];
#pragma unroll
        for (int i = 0; i < 4; i++)
#pragma unroll
            for (int j = 0; j < 2; j++)
                acc[i][j] = __builtin_amdgcn_mfma_f32_16x16x32_bf16(af[i], bf[j], acc[i][j], 0, 0, 0);
        if (kt < 15) {
            *(s16x8*)&An[cur ^ 1][rs * 40 + kq] = ra;
            *(s16x8*)&Bd[cur ^ 1][rs * 40 + kq] = rb;
        }
        __syncthreads();
    }
    size_t pbase = (((size_t)mc * B_ + b) * N_) * D_ + d0;
#pragma unroll
    for (int i = 0; i < 4; i++) {
        int nb = nw + i * 16 + quad * 4;
#pragma unroll
        for (int j = 0; j < 2; j++) {
            int d = dw + j * 16 + l15;
            f32x4 vv = acc[i][j];
            part[pbase + (size_t)(nb + 0) * D_ + d] = vv[0];
            part[pbase + (size_t)(nb + 1) * D_ + d] = vv[1];
            part[pbase + (size_t)(nb + 2) * D_ + d] = vv[2];
            part[pbase + (size_t)(nb + 3) * D_ + d] = vv[3];
        }
    }
}

// ---------------------------------------------------------------------------
// K4: per-expert linear (HBM-bound on W). Staging reduces the MC partials and
// normalizes by colsum. float4 W loads (16B/lane) with d-split across lane
// halves + shfl_xor(32) reduce -> half loop depth, 2x bytes in flight.
__global__ __launch_bounds__(256) void k_ys(const float* __restrict__ part,
                                            const float* __restrict__ colsum,
                                            const float* __restrict__ W,
                                            const float* __restrict__ bias,
                                            short* __restrict__ ysT) {
    __shared__ float xsn[B_][D_];
    int bi = blockIdx.x;
    int n = bi >> 2, eq = bi & 3;
    int tid = threadIdx.x;
    {
        int lb = tid >> 6, ld = (tid & 63) * 8;
        float inv = 1.0f / colsum[lb * N_ + n];
        float s0 = 0, s1 = 0, s2 = 0, s3 = 0, s4 = 0, s5 = 0, s6 = 0, s7 = 0;
#pragma unroll
        for (int mc = 0; mc < MC_; mc++) {
            const float* p = &part[(((size_t)mc * B_ + lb) * N_ + n) * D_ + ld];
            float4 v0 = *(const float4*)p;
            float4 v1 = *(const float4*)(p + 4);
            s0 += v0.x; s1 += v0.y; s2 += v0.z; s3 += v0.w;
            s4 += v1.x; s5 += v1.y; s6 += v1.z; s7 += v1.w;
        }
        float4 o0 = {s0 * inv, s1 * inv, s2 * inv, s3 * inv};
        float4 o1 = {s4 * inv, s5 * inv, s6 * inv, s7 * inv};
        *(float4*)&xsn[lb][ld] = o0;
        *(float4*)&xsn[lb][ld + 4] = o1;
    }
    __syncthreads();
    int b = tid >> 6;
    int lane = tid & 63;
    int dh = lane >> 5, l32 = lane & 31;
    int e = eq * 128 + l32 * 4;
    const float* Wn = W + (size_t)n * D_ * D_ + e;
    float a0 = 0.f, a1 = 0.f, a2 = 0.f, a3 = 0.f;
    int dbase = dh * 256;
#pragma unroll 8
    for (int d = dbase; d < dbase + 256; d++) {
        float4 w = *(const float4*)&Wn[(size_t)d * D_];
        float xv = xsn[b][d];
        a0 += xv * w.x;
        a1 += xv * w.y;
        a2 += xv * w.z;
        a3 += xv * w.w;
    }
    a0 += __shfl_xor(a0, 32, 64);
    a1 += __shfl_xor(a1, 32, 64);
    a2 += __shfl_xor(a2, 32, 64);
    a3 += __shfl_xor(a3, 32, 64);
    if (dh == 0) {
        float4 bv = *(const float4*)&bias[n * D_ + e];
        ysT[((size_t)b * D_ + e + 0) * N_ + n] = f2bf(a0 + bv.x);
        ysT[((size_t)b * D_ + e + 1) * N_ + n] = f2bf(a1 + bv.y);
        ysT[((size_t)b * D_ + e + 2) * N_ + n] = f2bf(a2 + bv.z);
        ysT[((size_t)b * D_ + e + 3) * N_ + n] = f2bf(a3 + bv.w);
    }
}

// ---------------------------------------------------------------------------
// K5: combine via bf16 MFMA — pure GEMM now. y[m][d] = sum_n ebn[m][n]*ysT[d][n].
// Block: 128m x 128d, K=n=128 in 4 chunks of 32. XCD-swizzled grid.
__global__ __launch_bounds__(256) void k_combine(const short* __restrict__ ebn,
                                                 const short* __restrict__ ysT,
                                                 float* __restrict__ y) {
    __shared__ short As[128 * 40];  // [m][n-chunk 0..31]
    __shared__ short Bs[128 * 40];  // [d][n-chunk 0..31]
    int t = threadIdx.x;
    int bid = blockIdx.x;
    int bi = (bid & 7) * 128 + (bid >> 3);  // 1024 blocks, 8 XCDs, chunk=128
    int dt = bi & 3, mt = bi >> 2;
    int r0 = mt * 128, d0 = dt * 128;
    int bb = r0 >> 13;
    int sm = t >> 1, nh = (t & 1) * 16;
    const short* erow = &ebn[(size_t)(r0 + sm) * N_ + nh];
    const short* yrow = &ysT[((size_t)bb * D_ + d0 + sm) * N_ + nh];
    int wid = t >> 6, lane = t & 63;
    int quad = lane >> 4, l15 = lane & 15;
    int mw = (wid >> 1) * 64, dw = (wid & 1) * 64;
    f32x4 acc[4][4] = {};

#pragma unroll
    for (int ks = 0; ks < 4; ks++) {
        int n0 = ks * 32;
        s16x8 ev0 = *(const s16x8*)&erow[n0];
        s16x8 ev1 = *(const s16x8*)&erow[n0 + 8];
        s16x8 yv0 = *(const s16x8*)&yrow[n0];
        s16x8 yv1 = *(const s16x8*)&yrow[n0 + 8];
        *(s16x8*)&As[sm * 40 + nh] = ev0;
        *(s16x8*)&As[sm * 40 + nh + 8] = ev1;
        *(s16x8*)&Bs[sm * 40 + nh] = yv0;
        *(s16x8*)&Bs[sm * 40 + nh + 8] = yv1;
        __syncthreads();
        s16x8 af[4], bf[4];
#pragma unroll
        for (int i = 0; i < 4; i++)
            af[i] = *(const s16x8*)&As[(mw + i * 16 + l15) * 40 + quad * 8];
#pragma unroll
        for (int j = 0; j < 4; j++)
            bf[j] = *(const s16x8*)&Bs[(dw + j * 16 + l15) * 40 + quad * 8];
#pragma unroll
        for (int i = 0; i < 4; i++)
#pragma unroll
            for (int j = 0; j < 4; j++)
                acc[i][j] = __builtin_amdgcn_mfma_f32_16x16x32_bf16(af[i], bf[j], acc[i][j], 0, 0, 0);
        __syncthreads();
    }
#pragma unroll
    for (int i = 0; i < 4; i++) {
        int mb = mw + i * 16 + quad * 4;
#pragma unroll
        for (int j = 0; j < 4; j++) {
            int d = d0 + dw + j * 16 + l15;
            f32x4 v = acc[i][j];
            y[(size_t)(r0 + mb + 0) * D_ + d] = v[0];
            y[(size_t)(r0 + mb + 1) * D_ + d] = v[1];
            y[(size_t)(r0 + mb + 2) * D_ + d] = v[2];
            y[(size_t)(r0 + mb + 3) * D_ + d] = v[3];
        }
    }
}

// ---------------------------------------------------------------------------
extern "C" void kernel_launch(void* const* d_in, const int* in_sizes, int n_in,
                              void* d_out, int out_size, void* d_ws, size_t ws_size,
                              hipStream_t stream) {
    const float* x = (const float*)d_in[0];
    const float* phi = (const float*)d_in[1];
    const float* scale = (const float*)d_in[2];
    const float* W = (const float*)d_in[3];
    const float* bias = (const float*)d_in[4];
    float* y = (float*)d_out;
    float* ws = (float*)d_ws;

    float* colsum = ws + OFF_CS;
    short* pbt = (short*)(ws + OFF_PBT);
    short* ebn = (short*)(ws + OFF_EBN);
    short* ewt = (short*)(ws + OFF_EWT);
    short* xbt = (short*)(ws + OFF_XBT);
    short* ysT = (short*)(ws + OFF_YST);
    float* part = ws + OFF_XP;

    hipMemsetAsync(colsum, 0, 512 * sizeof(float), stream);

    k_phinorm<<<N_, 128, 0, stream>>>(phi, scale, pbt);
    k_logits<<<TOK / 128, 512, 0, stream>>>(x, pbt, ebn, ewt, xbt, colsum);
    k_xs<<<B_ * MC_ * 4, 512, 0, stream>>>(ewt, xbt, part);
    k_ys<<<N_ * 4, 256, 0, stream>>>(part, colsum, W, bias, ysT);
    k_combine<<<(TOK / 128) * 4, 256, 0, stream>>>(ebn, ysT, y);
}

// Round 6
// 309.230 us; speedup vs baseline: 1.3672x; 1.0058x over previous
//
#include <hip/hip_runtime.h>
#include <math.h>

// Problem constants: B=4, M=8192, D=512, N=128, P=1
#define B_ 4
#define M_ 8192
#define D_ 512
#define N_ 128
#define TOK (B_ * M_)    // 32768
#define MC_ 16           // split-K chunks over M for xs
#define MLEN (M_ / MC_)  // 512 rows per chunk

// Workspace layout (float offsets)
#define OFF_CS 0                                   // [512] colsum of raw exp
#define OFF_PBT (OFF_CS + 512)                     // [N*D] bf16 phi^T (shorts)
#define OFF_EBN (OFF_PBT + N_ * D_ / 2)            // [TOK][N] bf16 E/rowsum (shorts)
#define OFF_EWT (OFF_EBN + (size_t)TOK * N_ / 2)   // [N][TOK] bf16 (E*rn)^T (shorts)
#define OFF_XBT (OFF_EWT + (size_t)N_ * TOK / 2)   // [D][TOK] bf16 raw-x^T (shorts)
#define OFF_YST (OFF_XBT + (size_t)D_ * TOK / 2)   // [B*D*N] bf16 ys^T (shorts)
#define OFF_XP (OFF_YST + B_ * D_ * N_ / 2)        // [MC*B*N*D] fp32 partials

typedef __attribute__((ext_vector_type(8))) short s16x8;
typedef __attribute__((ext_vector_type(4))) float f32x4;

__device__ inline short f2bf(float f) {  // RNE round to bf16
    union { float f; unsigned u; } v;
    v.f = f;
    unsigned r = v.u + 0x7fffu + ((v.u >> 16) & 1u);
    return (short)(r >> 16);
}

// v_cvt_pk_bf16_f32: D[15:0]=bf16(a), D[31:16]=bf16(b), RNE (bit-identical to f2bf)
__device__ inline unsigned cvtpk(float a, float b) {
    unsigned d;
    asm("v_cvt_pk_bf16_f32 %0, %1, %2" : "=v"(d) : "v"(a), "v"(b));
    return d;
}

// ---------------------------------------------------------------------------
// K0: phi col-normalize -> pbt[n][d] bf16 = scale * phi[d][n]/max(||phi[:,n]||,eps)
__global__ __launch_bounds__(128) void k_phinorm(const float* __restrict__ phi,
                                                 const float* __restrict__ scale,
                                                 short* __restrict__ pbt) {
    __shared__ float sred[128];
    int n = blockIdx.x, tid = threadIdx.x;
    float ss = 0.f;
    for (int d = tid; d < D_; d += 128) {
        float v = phi[d * N_ + n];
        ss += v * v;
    }
    sred[tid] = ss;
    __syncthreads();
    for (int s = 64; s > 0; s >>= 1) {
        if (tid < s) sred[tid] += sred[tid + s];
        __syncthreads();
    }
    float sc = scale[0] / fmaxf(sqrtf(sred[0]), 1e-12f);
    for (int d = tid; d < D_; d += 128) pbt[n * D_ + d] = f2bf(phi[d * N_ + n] * sc);
}

// ---------------------------------------------------------------------------
// K1: logits. 128m x 128n tile, 512 thr (8 waves, 4x2). Double-buffered LDS,
// one barrier per K-step, next-step loads issued before the MFMAs. MFMA on
// raw bf16(x); rn applied in epilogue. bf16 conversion via v_cvt_pk_bf16_f32
// (1 instr / 2 values vs 4 ops/value manual RNE). Per K-step transpose-writes
// As tile to xbt[d][m]. Epilogue: ebn[m][n]=bf16(E/rowsum), ewt[n][m]=
// bf16(E*rn), colsum atomics.
__global__ __launch_bounds__(512) void k_logits(const float* __restrict__ x,
                                                const short* __restrict__ pbt,
                                                short* __restrict__ ebn,
                                                short* __restrict__ ewt,
                                                short* __restrict__ xbt,
                                                float* __restrict__ colsum) {
    __shared__ short smem[4 * 128 * 40];  // As dbuf | Bs dbuf; T/T2 overlay after loop
    __shared__ float rnS[128];
    __shared__ float rsH[2][128];

    int t = threadIdx.x;
    int r0 = blockIdx.x * 128;
    int sm = t >> 2;           // staging row (m for A, n for B)
    int kq = (t & 3) * 8;      // k sub-chunk
    const float* xrow = &x[(size_t)(r0 + sm) * D_ + kq];
    const short* brow = &pbt[sm * D_ + kq];
    int wid = t >> 6, lane = t & 63;
    int quad = lane >> 4, l15 = lane & 15;
    int mw = (wid >> 1) * 32, nw = (wid & 1) * 64;
    int dl = t & 31, mg = t >> 5;  // xbt transpose mapping: 32 d x 16 m-groups
    f32x4 acc[2][4] = {};
    float ss = 0.f;

    {  // prologue: stage k-step 0
        float4 a0 = *(const float4*)&xrow[0];
        float4 a1 = *(const float4*)&xrow[4];
        s16x8 bv = *(const s16x8*)&brow[0];
        ss += a0.x * a0.x + a0.y * a0.y + a0.z * a0.z + a0.w * a0.w +
              a1.x * a1.x + a1.y * a1.y + a1.z * a1.z + a1.w * a1.w;
        uint4 av;
        av.x = cvtpk(a0.x, a0.y); av.y = cvtpk(a0.z, a0.w);
        av.z = cvtpk(a1.x, a1.y); av.w = cvtpk(a1.z, a1.w);
        *(uint4*)&smem[0 * 5120 + sm * 40 + kq] = av;
        *(s16x8*)&smem[10240 + 0 * 5120 + sm * 40 + kq] = bv;
    }
    __syncthreads();

#pragma unroll
    for (int kt = 0; kt < 16; kt++) {
        int cur = kt & 1;
        short* As = &smem[cur * 5120];
        short* Bs = &smem[10240 + cur * 5120];
        float4 na0, na1;
        s16x8 nbv;
        if (kt < 15) {  // issue next-step loads; in flight under MFMA
            na0 = *(const float4*)&xrow[(kt + 1) * 32];
            na1 = *(const float4*)&xrow[(kt + 1) * 32 + 4];
            nbv = *(const s16x8*)&brow[(kt + 1) * 32];
        }
        s16x8 af[2], bfr[4];
#pragma unroll
        for (int i = 0; i < 2; i++)
            af[i] = *(const s16x8*)&As[(mw + i * 16 + l15) * 40 + quad * 8];
#pragma unroll
        for (int j = 0; j < 4; j++)
            bfr[j] = *(const s16x8*)&Bs[(nw + j * 16 + l15) * 40 + quad * 8];
#pragma unroll
        for (int i = 0; i < 2; i++)
#pragma unroll
            for (int j = 0; j < 4; j++)
                acc[i][j] = __builtin_amdgcn_mfma_f32_16x16x32_bf16(af[i], bfr[j], acc[i][j], 0, 0, 0);
        {  // transpose-write raw-x tile to xbt[d][m]
            s16x8 tv;
#pragma unroll
            for (int r = 0; r < 8; r++) tv[r] = As[(mg * 8 + r) * 40 + dl];
            *(s16x8*)&xbt[(size_t)(kt * 32 + dl) * TOK + r0 + mg * 8] = tv;
        }
        if (kt < 15) {  // convert + stage into other buffer
            ss += na0.x * na0.x + na0.y * na0.y + na0.z * na0.z + na0.w * na0.w +
                  na1.x * na1.x + na1.y * na1.y + na1.z * na1.z + na1.w * na1.w;
            uint4 nav;
            nav.x = cvtpk(na0.x, na0.y); nav.y = cvtpk(na0.z, na0.w);
            nav.z = cvtpk(na1.x, na1.y); nav.w = cvtpk(na1.z, na1.w);
            *(uint4*)&smem[(cur ^ 1) * 5120 + sm * 40 + kq] = nav;
            *(s16x8*)&smem[10240 + (cur ^ 1) * 5120 + sm * 40 + kq] = nbv;
        }
        __syncthreads();
    }
    // row inverse norms: 4 consecutive lanes share a row
    ss += __shfl_xor(ss, 1, 64);
    ss += __shfl_xor(ss, 2, 64);
    if ((t & 3) == 0) rnS[sm] = 1.0f / fmaxf(sqrtf(ss), 1e-12f);
    __syncthreads();

    int bb = r0 >> 13;
    float rv[2][4];
#pragma unroll
    for (int i = 0; i < 2; i++) {
        int ml = mw + i * 16 + quad * 4;
        rv[i][0] = rnS[ml]; rv[i][1] = rnS[ml + 1];
        rv[i][2] = rnS[ml + 2]; rv[i][3] = rnS[ml + 3];
    }
    // exp (raw, kept in acc), colsum atomics, per-row partial sums, ewt values
    float rs[2][4] = {};
    uint2 ebf[2][4];
#pragma unroll
    for (int j = 0; j < 4; j++) {
        int n = nw + j * 16 + l15;
        float cs = 0.f;
#pragma unroll
        for (int i = 0; i < 2; i++) {
            f32x4 vv = acc[i][j];
            float e0 = __expf(vv[0] * rv[i][0]), e1 = __expf(vv[1] * rv[i][1]);
            float e2 = __expf(vv[2] * rv[i][2]), e3 = __expf(vv[3] * rv[i][3]);
            acc[i][j][0] = e0; acc[i][j][1] = e1; acc[i][j][2] = e2; acc[i][j][3] = e3;
            cs += e0 + e1 + e2 + e3;
            rs[i][0] += e0; rs[i][1] += e1; rs[i][2] += e2; rs[i][3] += e3;
            ebf[i][j].x = cvtpk(e0 * rv[i][0], e1 * rv[i][1]);
            ebf[i][j].y = cvtpk(e2 * rv[i][2], e3 * rv[i][3]);
        }
        cs += __shfl_xor(cs, 16, 64);
        cs += __shfl_xor(cs, 32, 64);
        if (lane < 16) atomicAdd(&colsum[bb * N_ + n], cs);
    }
    // rowsum: reduce over the 16 l15 lanes, combine the two n-half waves via LDS
#pragma unroll
    for (int off = 1; off <= 8; off <<= 1)
#pragma unroll
        for (int i = 0; i < 2; i++)
#pragma unroll
            for (int r = 0; r < 4; r++) rs[i][r] += __shfl_xor(rs[i][r], off, 64);
    if (l15 == 0) {
#pragma unroll
        for (int i = 0; i < 2; i++)
#pragma unroll
            for (int r = 0; r < 4; r++)
                rsH[wid & 1][mw + i * 16 + quad * 4 + r] = rs[i][r];
    }
    __syncthreads();
    float ri[2][4];
#pragma unroll
    for (int i = 0; i < 2; i++)
#pragma unroll
        for (int r = 0; r < 4; r++) {
            int m = mw + i * 16 + quad * 4 + r;
            ri[i][r] = 1.0f / (rsH[0][m] + rsH[1][m]);
        }

    // ewt[n][r0..r0+127] = bf16(E*rn) via LDS transpose, two 64-row n-halves
    short* T = smem;  // 64 x 136 shorts
#pragma unroll
    for (int h = 0; h < 2; h++) {
        if ((wid & 1) == h) {
#pragma unroll
            for (int i = 0; i < 2; i++) {
                int mb = mw + i * 16 + quad * 4;  // local m 0..127
#pragma unroll
                for (int j = 0; j < 4; j++) {
                    int nl = j * 16 + l15;       // local n within half 0..63
                    *(uint2*)&T[nl * 136 + mb] = ebf[i][j];
                }
            }
        }
        __syncthreads();
        {
            int nl = t >> 3, c = t & 7;
            s16x8 v0 = *(const s16x8*)&T[nl * 136 + c * 16];
            s16x8 v1 = *(const s16x8*)&T[nl * 136 + c * 16 + 8];
            size_t go = (size_t)(h * 64 + nl) * TOK + r0 + c * 16;
            *(s16x8*)&ewt[go] = v0;
            *(s16x8*)&ewt[go + 8] = v1;
        }
        __syncthreads();
    }

    // ebn[m][n] = bf16(E/rowsum), staged in LDS -> fully coalesced stores
    short* T2 = smem;  // 128 x 136 shorts (34816 B <= 40960 B)
#pragma unroll
    for (int j = 0; j < 4; j++) {
        int n = nw + j * 16 + l15;
#pragma unroll
        for (int i = 0; i < 2; i++) {
            int m = mw + i * 16 + quad * 4;
            f32x4 vv = acc[i][j];
            unsigned w01 = cvtpk(vv[0] * ri[i][0], vv[1] * ri[i][1]);
            unsigned w23 = cvtpk(vv[2] * ri[i][2], vv[3] * ri[i][3]);
            T2[(m + 0) * 136 + n] = (short)(w01 & 0xffffu);
            T2[(m + 1) * 136 + n] = (short)(w01 >> 16);
            T2[(m + 2) * 136 + n] = (short)(w23 & 0xffffu);
            T2[(m + 3) * 136 + n] = (short)(w23 >> 16);
        }
    }
    __syncthreads();
    {
        int row = t >> 2, c = (t & 3) * 32;
        s16x8 v0 = *(const s16x8*)&T2[row * 136 + c];
        s16x8 v1 = *(const s16x8*)&T2[row * 136 + c + 8];
        s16x8 v2 = *(const s16x8*)&T2[row * 136 + c + 16];
        s16x8 v3 = *(const s16x8*)&T2[row * 136 + c + 24];
        size_t go = (size_t)(r0 + row) * N_ + c;
        *(s16x8*)&ebn[go] = v0;
        *(s16x8*)&ebn[go + 8] = v1;
        *(s16x8*)&ebn[go + 16] = v2;
        *(s16x8*)&ebn[go + 24] = v3;
    }
}

// ---------------------------------------------------------------------------
// K3: xs partials via bf16 MFMA. part[mc][b][n][d] = sum_m ewt[n][m]*xbt[d][m].
// 512 thr (8 waves = 2/SIMD), tile 128n x 128d, K=512 m. Double-buffered LDS,
// one barrier per K-step, loads prefetched under MFMA. XCD-swizzled grid.
__global__ __launch_bounds__(512) void k_xs(const short* __restrict__ ewt,
                                            const short* __restrict__ xbt,
                                            float* __restrict__ part) {
    __shared__ short An[2][128 * 40];  // [n][k-chunk 0..31]
    __shared__ short Bd[2][128 * 40];  // [d][k-chunk 0..31]
    int t = threadIdx.x;
    int bid = blockIdx.x;
    int bi = (bid & 7) * 32 + (bid >> 3);  // 256 blocks, 8 XCDs, chunk=32
    int dt = bi & 3, mc = (bi >> 2) & 15, b = bi >> 6;
    int d0 = dt * 128;
    size_t mbase = (size_t)b * M_ + (size_t)mc * MLEN;
    int rs = t >> 2, kq = (t & 3) * 8;
    const short* arow = &ewt[(size_t)rs * TOK + mbase + kq];
    const short* brow = &xbt[(size_t)(d0 + rs) * TOK + mbase + kq];
    int wid = t >> 6, lane = t & 63;
    int quad = lane >> 4, l15 = lane & 15;
    int nw = (wid >> 2) * 64, dw = (wid & 3) * 32;
    f32x4 acc[4][2] = {};

    {
        s16x8 ra = *(const s16x8*)&arow[0];
        s16x8 rb = *(const s16x8*)&brow[0];
        *(s16x8*)&An[0][rs * 40 + kq] = ra;
        *(s16x8*)&Bd[0][rs * 40 + kq] = rb;
    }
    __syncthreads();

#pragma unroll
    for (int kt = 0; kt < 16; kt++) {
        int cur = kt & 1;
        s16x8 ra, rb;
        if (kt < 15) {
            ra = *(const s16x8*)&arow[(kt + 1) * 32];
            rb = *(const s16x8*)&brow[(kt + 1) * 32];
        }
        s16x8 af[4], bf[2];
#pragma unroll
        for (int i = 0; i < 4; i++)
            af[i] = *(const s16x8*)&An[cur][(nw + i * 16 + l15) * 40 + quad * 8];
#pragma unroll
        for (int j = 0; j < 2; j++)
            bf[j] = *(const s16x8*)&Bd[cur][(dw + j * 16 + l15) * 40 + quad * 8];
#pragma unroll
        for (int i = 0; i < 4; i++)
#pragma unroll
            for (int j = 0; j < 2; j++)
                acc[i][j] = __builtin_amdgcn_mfma_f32_16x16x32_bf16(af[i], bf[j], acc[i][j], 0, 0, 0);
        if (kt < 15) {
            *(s16x8*)&An[cur ^ 1][rs * 40 + kq] = ra;
            *(s16x8*)&Bd[cur ^ 1][rs * 40 + kq] = rb;
        }
        __syncthreads();
    }
    size_t pbase = (((size_t)mc * B_ + b) * N_) * D_ + d0;
#pragma unroll
    for (int i = 0; i < 4; i++) {
        int nb = nw + i * 16 + quad * 4;
#pragma unroll
        for (int j = 0; j < 2; j++) {
            int d = dw + j * 16 + l15;
            f32x4 vv = acc[i][j];
            part[pbase + (size_t)(nb + 0) * D_ + d] = vv[0];
            part[pbase + (size_t)(nb + 1) * D_ + d] = vv[1];
            part[pbase + (size_t)(nb + 2) * D_ + d] = vv[2];
            part[pbase + (size_t)(nb + 3) * D_ + d] = vv[3];
        }
    }
}

// ---------------------------------------------------------------------------
// K4: per-expert linear (HBM-bound on W). Staging reduces the MC partials and
// normalizes by colsum. Each thread accumulates ALL 4 b's (W element loaded
// once per block, not 4x); 8-way d-split reduced via shfl + LDS. eq-sibling
// blocks land on the same XCD (part re-reads become L2-local).
__global__ __launch_bounds__(256) void k_ys(const float* __restrict__ part,
                                            const float* __restrict__ colsum,
                                            const float* __restrict__ W,
                                            const float* __restrict__ bias,
                                            short* __restrict__ ysT) {
    __shared__ float xsn[B_][D_];
    __shared__ float red[4][32][17];  // +1 pad: conflict-free scalar access
    int bid = blockIdx.x;
    int bi = (bid & 7) * 64 + (bid >> 3);  // 512 blocks, 8 XCDs, chunk=64
    int n = bi >> 2, eq = bi & 3;
    int tid = threadIdx.x;
    {
        int lb = tid >> 6, ld = (tid & 63) * 8;
        float inv = 1.0f / colsum[lb * N_ + n];
        float s0 = 0, s1 = 0, s2 = 0, s3 = 0, s4 = 0, s5 = 0, s6 = 0, s7 = 0;
#pragma unroll
        for (int mc = 0; mc < MC_; mc++) {
            const float* p = &part[(((size_t)mc * B_ + lb) * N_ + n) * D_ + ld];
            float4 v0 = *(const float4*)p;
            float4 v1 = *(const float4*)(p + 4);
            s0 += v0.x; s1 += v0.y; s2 += v0.z; s3 += v0.w;
            s4 += v1.x; s5 += v1.y; s6 += v1.z; s7 += v1.w;
        }
        float4 o0 = {s0 * inv, s1 * inv, s2 * inv, s3 * inv};
        float4 o1 = {s4 * inv, s5 * inv, s6 * inv, s7 * inv};
        *(float4*)&xsn[lb][ld] = o0;
        *(float4*)&xsn[lb][ld + 4] = o1;
    }
    __syncthreads();
    int l32 = tid & 31, dh = tid >> 5;  // 8 d-groups x 64 d each
    int e = eq * 128 + l32 * 4;
    const float* Wn = W + (size_t)n * D_ * D_ + e;
    float a[4][4] = {};  // [b][e-component]
    int dbase = dh * 64;
#pragma unroll 2
    for (int dc = 0; dc < 64; dc += 4) {
        int d = dbase + dc;
        f32x4 xv[4];
#pragma unroll
        for (int b = 0; b < 4; b++) xv[b] = *(const f32x4*)&xsn[b][d];
#pragma unroll
        for (int u = 0; u < 4; u++) {
            float4 w = *(const float4*)&Wn[(size_t)(d + u) * D_];
#pragma unroll
            for (int b = 0; b < 4; b++) {
                a[b][0] += xv[b][u] * w.x;
                a[b][1] += xv[b][u] * w.y;
                a[b][2] += xv[b][u] * w.z;
                a[b][3] += xv[b][u] * w.w;
            }
        }
    }
    // combine the 2 dh-groups within each wave, then 4 waves via LDS
#pragma unroll
    for (int b = 0; b < 4; b++)
#pragma unroll
        for (int c = 0; c < 4; c++) a[b][c] += __shfl_xor(a[b][c], 32, 64);
    int wv = tid >> 6, lane = tid & 63;
    if (lane < 32) {
#pragma unroll
        for (int b = 0; b < 4; b++)
#pragma unroll
            for (int c = 0; c < 4; c++) red[wv][lane][b * 4 + c] = a[b][c];
    }
    __syncthreads();
    if (tid < 128) {
        int b = tid >> 5, l = tid & 31;
        float r0 = 0, r1 = 0, r2 = 0, r3 = 0;
#pragma unroll
        for (int w = 0; w < 4; w++) {
            r0 += red[w][l][b * 4 + 0];
            r1 += red[w][l][b * 4 + 1];
            r2 += red[w][l][b * 4 + 2];
            r3 += red[w][l][b * 4 + 3];
        }
        int ee = eq * 128 + l * 4;
        float4 bv = *(const float4*)&bias[n * D_ + ee];
        ysT[((size_t)b * D_ + ee + 0) * N_ + n] = f2bf(r0 + bv.x);
        ysT[((size_t)b * D_ + ee + 1) * N_ + n] = f2bf(r1 + bv.y);
        ysT[((size_t)b * D_ + ee + 2) * N_ + n] = f2bf(r2 + bv.z);
        ysT[((size_t)b * D_ + ee + 3) * N_ + n] = f2bf(r3 + bv.w);
    }
}

// ---------------------------------------------------------------------------
// K5: combine via bf16 MFMA — pure GEMM. y[m][d] = sum_n ebn[m][n]*ysT[d][n].
// Block: 128m x 128d, K=n=128 in 4 chunks of 32. XCD-swizzled grid.
__global__ __launch_bounds__(256) void k_combine(const short* __restrict__ ebn,
                                                 const short* __restrict__ ysT,
                                                 float* __restrict__ y) {
    __shared__ short As[128 * 40];  // [m][n-chunk 0..31]
    __shared__ short Bs[128 * 40];  // [d][n-chunk 0..31]
    int t = threadIdx.x;
    int bid = blockIdx.x;
    int bi = (bid & 7) * 128 + (bid >> 3);  // 1024 blocks, 8 XCDs, chunk=128
    int dt = bi & 3, mt = bi >> 2;
    int r0 = mt * 128, d0 = dt * 128;
    int bb = r0 >> 13;
    int sm = t >> 1, nh = (t & 1) * 16;
    const short* erow = &ebn[(size_t)(r0 + sm) * N_ + nh];
    const short* yrow = &ysT[((size_t)bb * D_ + d0 + sm) * N_ + nh];
    int wid = t >> 6, lane = t & 63;
    int quad = lane >> 4, l15 = lane & 15;
    int mw = (wid >> 1) * 64, dw = (wid & 1) * 64;
    f32x4 acc[4][4] = {};

#pragma unroll
    for (int ks = 0; ks < 4; ks++) {
        int n0 = ks * 32;
        s16x8 ev0 = *(const s16x8*)&erow[n0];
        s16x8 ev1 = *(const s16x8*)&erow[n0 + 8];
        s16x8 yv0 = *(const s16x8*)&yrow[n0];
        s16x8 yv1 = *(const s16x8*)&yrow[n0 + 8];
        *(s16x8*)&As[sm * 40 + nh] = ev0;
        *(s16x8*)&As[sm * 40 + nh + 8] = ev1;
        *(s16x8*)&Bs[sm * 40 + nh] = yv0;
        *(s16x8*)&Bs[sm * 40 + nh + 8] = yv1;
        __syncthreads();
        s16x8 af[4], bf[4];
#pragma unroll
        for (int i = 0; i < 4; i++)
            af[i] = *(const s16x8*)&As[(mw + i * 16 + l15) * 40 + quad * 8];
#pragma unroll
        for (int j = 0; j < 4; j++)
            bf[j] = *(const s16x8*)&Bs[(dw + j * 16 + l15) * 40 + quad * 8];
#pragma unroll
        for (int i = 0; i < 4; i++)
#pragma unroll
            for (int j = 0; j < 4; j++)
                acc[i][j] = __builtin_amdgcn_mfma_f32_16x16x32_bf16(af[i], bf[j], acc[i][j], 0, 0, 0);
        __syncthreads();
    }
#pragma unroll
    for (int i = 0; i < 4; i++) {
        int mb = mw + i * 16 + quad * 4;
#pragma unroll
        for (int j = 0; j < 4; j++) {
            int d = d0 + dw + j * 16 + l15;
            f32x4 v = acc[i][j];
            y[(size_t)(r0 + mb + 0) * D_ + d] = v[0];
            y[(size_t)(r0 + mb + 1) * D_ + d] = v[1];
            y[(size_t)(r0 + mb + 2) * D_ + d] = v[2];
            y[(size_t)(r0 + mb + 3) * D_ + d] = v[3];
        }
    }
}

// ---------------------------------------------------------------------------
extern "C" void kernel_launch(void* const* d_in, const int* in_sizes, int n_in,
                              void* d_out, int out_size, void* d_ws, size_t ws_size,
                              hipStream_t stream) {
    const float* x = (const float*)d_in[0];
    const float* phi = (const float*)d_in[1];
    const float* scale = (const float*)d_in[2];
    const float* W = (const float*)d_in[3];
    const float* bias = (const float*)d_in[4];
    float* y = (float*)d_out;
    float* ws = (float*)d_ws;

    float* colsum = ws + OFF_CS;
    short* pbt = (short*)(ws + OFF_PBT);
    short* ebn = (short*)(ws + OFF_EBN);
    short* ewt = (short*)(ws + OFF_EWT);
    short* xbt = (short*)(ws + OFF_XBT);
    short* ysT = (short*)(ws + OFF_YST);
    float* part = ws + OFF_XP;

    hipMemsetAsync(colsum, 0, 512 * sizeof(float), stream);

    k_phinorm<<<N_, 128, 0, stream>>>(phi, scale, pbt);
    k_logits<<<TOK / 128, 512, 0, stream>>>(x, pbt, ebn, ewt, xbt, colsum);
    k_xs<<<B_ * MC_ * 4, 512, 0, stream>>>(ewt, xbt, part);
    k_ys<<<N_ * 4, 256, 0, stream>>>(part, colsum, W, bias, ysT);
    k_combine<<<(TOK / 128) * 4, 256, 0, stream>>>(ebn, ysT, y);
}